// Round 9
// baseline (209.308 us; speedup 1.0000x reference)
//
#include <hip/hip_runtime.h>

#define LAMBDA_COORD 5.0f
#define LAMBDA_NOOBJ 0.5f
#define WH_EPS 1e-6f
#define IOU_EPS 1e-6f

constexpr int BLOCKS = 1792;   // 7168 waves; 100352 groups / 7168 = 14 iterations exactly

// One group = 4 cell-pairs = 8 cells = 60 float4 per array (960 B), handled by
// one wave per iteration. Lanes 0..59 stream; lanes 0..7 additionally own one
// cell each for the iou-dependent terms (re-reading 40 B from global — same
// lines the stream is fetching this iteration -> L1/L2 hits).
__global__ __launch_bounds__(256) void yolo_loss_kernel(
    const float* __restrict__ t_g, const float* __restrict__ p_g,
    float* __restrict__ out, int ngroups, float inv_batch) {
    const int lane = threadIdx.x & 63;
    const int widx = threadIdx.x >> 6;
    const int wave_id = blockIdx.x * 4 + widx;
    const int nwaves = BLOCKS * 4;

    const int u = lane % 15;        // float4 index within pair
    const int bbase = lane - u;     // first lane of this pair-group
    const bool active = lane < 60;
    const bool sideA = (u <= 7);    // this lane's class floats belong to cell A

    // Class-float masks: pair floats 10..29 (cell A) and 40..59 (cell B).
    float cm[4];
#pragma unroll
    for (int j = 0; j < 4; ++j) {
        int idx = 4 * u + j;
        cm[j] = ((idx >= 10 && idx < 30) || idx >= 40) ? 1.0f : 0.0f;
    }

    const float4* tv = (const float4*)t_g;
    const float4* pv = (const float4*)p_g;

    float v = 0.0f;

    for (int g = wave_id; g < ngroups; g += nwaves) {
        // ---- streaming loads (perfectly coalesced, lanes 0..59) ----
        float4 T = make_float4(0.f, 0.f, 0.f, 0.f);
        float4 P = make_float4(0.f, 0.f, 0.f, 0.f);
        if (active) {
            size_t b = (size_t)g * 60 + lane;
            T = tv[b];
            P = pv[b];
        }

        // ---- per-cell gather loads (lanes 0..7; L1/L2-warm re-reads) ----
        float2 a01 = {0.f, 0.f}, a23 = {0.f, 0.f};
        float2 q01 = {0.f, 0.f}, q23 = {0.f, 0.f}, q45 = {0.f, 0.f},
               q67 = {0.f, 0.f}, q89 = {0.f, 0.f};
        float tt4 = 0.f;
        if (lane < 8) {
            const size_t cb = ((size_t)g * 8 + lane) * 30;   // float offset, even
            const float2* tc = (const float2*)(t_g + cb);
            const float2* pc = (const float2*)(p_g + cb);
            a01 = tc[0]; a23 = tc[1];          // t0,t1 | t2,t3
            tt4 = t_g[cb + 4];                 // t4
            q01 = pc[0]; q23 = pc[1];          // p0,p1 | p2,p3
            q45 = pc[2]; q67 = pc[3];          // p4,p5 | p6,p7
            q89 = pc[4];                       // p8,p9
        }

        // ---- elementwise: masked class SSE ----
        float d0 = T.x - P.x, d1 = T.y - P.y, d2 = T.z - P.z, d3 = T.w - P.w;
        float s_cls = d0 * d0 * cm[0] + d1 * d1 * cm[1] +
                      d2 * d2 * cm[2] + d3 * d3 * cm[3];

        // Objectness broadcast: t4A = T.x of lane bbase+1; t4B = T.z of bbase+8.
        float t4A = __shfl(T.x, bbase + 1, 64);
        float t4B = __shfl(T.z, bbase + 8, 64);
        float t4s = sideA ? t4A : t4B;
        float objm = (t4s == 1.0f) ? 1.0f : 0.0f;
        v += s_cls * objm;                      // cls term (obj cells only)

        // ---- elementwise: noobj conf terms (owners of p4/p9 per cell) ----
        // A: p4 = #1.x (u==1), p9 = #2.y (u==2); B: p4 = #8.z, p9 = #9.w.
        float nb = 0.f;
        if (u == 1)      { float d = t4A - P.x; nb = d * d; }
        else if (u == 2) { float d = t4A - P.y; nb = d * d; }
        else if (u == 8) { float d = t4B - P.z; nb = d * d; }
        else if (u == 9) { float d = t4B - P.w; nb = d * d; }
        if (active) v += LAMBDA_NOOBJ * nb * (1.0f - objm);

        // ---- per-cell iou-dependent terms (once per cell, lanes 0..7) ----
        {
            float ax1 = a01.x - a23.x * 0.5f, ay1 = a01.y - a23.y * 0.5f;
            float ax2 = a01.x + a23.x * 0.5f, ay2 = a01.y + a23.y * 0.5f;
            float area_a = fabsf((ax2 - ax1) * (ay2 - ay1));

            // box1 = p0..p3, box2 = p5..p8
            float b1x1 = q01.x - q23.x * 0.5f, b1y1 = q01.y - q23.y * 0.5f;
            float b1x2 = q01.x + q23.x * 0.5f, b1y2 = q01.y + q23.y * 0.5f;
            float b2x1 = q45.y - q67.y * 0.5f, b2y1 = q67.x - q89.x * 0.5f;
            float b2x2 = q45.y + q67.y * 0.5f, b2y2 = q67.x + q89.x * 0.5f;

            float iw1 = fmaxf(fminf(ax2, b1x2) - fmaxf(ax1, b1x1), 0.0f);
            float ih1 = fmaxf(fminf(ay2, b1y2) - fmaxf(ay1, b1y1), 0.0f);
            float in1 = iw1 * ih1;
            float ar1 = fabsf((b1x2 - b1x1) * (b1y2 - b1y1));
            float iou1 = in1 / (area_a + ar1 - in1 + IOU_EPS);

            float iw2 = fmaxf(fminf(ax2, b2x2) - fmaxf(ax1, b2x1), 0.0f);
            float ih2 = fmaxf(fminf(ay2, b2y2) - fmaxf(ay1, b2y1), 0.0f);
            float in2 = iw2 * ih2;
            float ar2 = fabsf((b2x2 - b2x1) * (b2y2 - b2y1));
            float iou2 = in2 / (area_a + ar2 - in2 + IOU_EPS);

            bool use1 = iou1 > iou2;
            float bh0 = use1 ? q01.x : q45.y;
            float bh1 = use1 ? q01.y : q67.x;
            float bh2 = use1 ? q23.x : q67.y;
            float bh3 = use1 ? q23.y : q89.x;
            float cc  = use1 ? q45.x : q89.y;
            float co  = use1 ? q89.y : q45.x;

            float dx = a01.x - bh0, dy = a01.y - bh1;
            float xy = LAMBDA_COORD * (dx * dx + dy * dy);

            float sw = sqrtf(a23.x) - sqrtf(fabsf(bh2 + WH_EPS));
            float sh = sqrtf(a23.y) - sqrtf(fabsf(bh3 + WH_EPS));
            float wh = LAMBDA_COORD * (sw * sw + sh * sh);

            float dc = tt4 - cc;
            float obj_part = xy + wh + dc * dc + LAMBDA_NOOBJ * co * co;

            if (lane < 8 && tt4 == 1.0f) v += obj_part;
        }
    }

    // wave64 reduction -> per-wave LDS -> one atomic per block
#pragma unroll
    for (int off = 32; off > 0; off >>= 1)
        v += __shfl_down(v, off, 64);

    __shared__ float swave[4];
    if ((threadIdx.x & 63) == 0) swave[widx] = v;
    __syncthreads();
    if (threadIdx.x == 0) {
        float s = swave[0] + swave[1] + swave[2] + swave[3];
        atomicAdd(out, s * inv_batch);
    }
}

extern "C" void kernel_launch(void* const* d_in, const int* in_sizes, int n_in,
                              void* d_out, int out_size, void* d_ws, size_t ws_size,
                              hipStream_t stream) {
    const float* t = (const float*)d_in[0];  // y_trues
    const float* p = (const float*)d_in[1];  // y_preds
    float* out = (float*)d_out;

    const int total = in_sizes[0];        // 24,084,480
    const int cells = total / 30;         // 802,816
    const int ngroups = cells / 8;        // 100,352 (exact)
    const int batch = cells / 49;         // 16,384
    const float inv_batch = 1.0f / (float)batch;

    // d_out is poisoned (0xAA) before every replay — zero it on-stream.
    hipMemsetAsync(out, 0, sizeof(float), stream);

    yolo_loss_kernel<<<BLOCKS, 256, 0, stream>>>(t, p, out, ngroups, inv_batch);
}